// Round 1
// baseline (306.373 us; speedup 1.0000x reference)
//
#include <hip/hip_runtime.h>

#define HH 8
#define NN 32
#define TT 2048
#define DD 256
#define KPERM 1

typedef float f4 __attribute__((ext_vector_type(4)));
typedef float f32x4 __attribute__((ext_vector_type(4)));
typedef __bf16 bf16x8 __attribute__((ext_vector_type(8)));
typedef unsigned short u16;
typedef u16 u16x4 __attribute__((ext_vector_type(4)));
typedef u16 u16x8 __attribute__((ext_vector_type(8)));

__device__ __forceinline__ u16 f2bf(float x) {
  unsigned u = __float_as_uint(x);
  return (u16)((u + 0x7fffu + ((u >> 16) & 1u)) >> 16);
}
__device__ __forceinline__ float bf2f(u16 b) { return __uint_as_float(((unsigned)b) << 16); }

__device__ __forceinline__ float ftanh(float x) {
  float ax = __builtin_fabsf(x);
  float e = __expf(ax + ax);
  float t = 1.f - 2.f / (e + 1.f);
  return x < 0.f ? -t : t;
}

// k-permutation: source k index c (0..31) -> stored position within a 32-elem row.
// Matches MFMA 16x16x32 operand layout hypothesis H2: lane l element b holds
// k = (l>>4)*4 + (b&3) + 16*(b>>2); stored so one b128 read = one fragment.
__device__ __forceinline__ int kperm(int c) {
#if KPERM
  return (c & 3) | (((c >> 2) & 3) << 3) | (((c >> 4) & 1) << 2);
#else
  return c;
#endif
}
__device__ __forceinline__ int kperm_inv(int p) {
#if KPERM
  return (p & 3) | (((p >> 2) & 1) << 4) | ((p >> 3) << 2);
#else
  return p;
#endif
}

__device__ __forceinline__ void gl_lds16(const void* g, void* l) {
  __builtin_amdgcn_global_load_lds((const __attribute__((address_space(1))) unsigned*)g,
                                   (__attribute__((address_space(3))) unsigned*)l, 16, 0, 0);
}

// ---------------------------------------------------------------------------
// Kernel 0: pack Wm [H][256 e][256 d] fp32 -> bf16 hi/lo, laid out as the exact
// linear LDS image consumed via global_load_lds by k_scores:
//   [h][kstep(8)][half(hi=0,lo=1)][e(256)][32 bf16 row, XOR-swizzled + kperm'd]
// ---------------------------------------------------------------------------
__global__ void k_pack(const float* __restrict__ wm, u16* __restrict__ pk) {
  int u = blockIdx.x * 256 + threadIdx.x;   // 131072 threads, 8 u16 each
  int pos0 = (u & 3) << 3;
  int e    = (u >> 2) & 255;
  int half = (u >> 10) & 1;
  int ks   = (u >> 11) & 7;
  int h    = u >> 14;
  int sw = ((e >> 1) & 3) << 3;             // swizzle in u16 units (16B blocks)
  const float* src = wm + ((size_t)(h * 256 + e) << 8);
  u16 outv[8];
#pragma unroll
  for (int j = 0; j < 8; ++j) {
    int p = pos0 + j;
    int kp = p ^ sw;
    int c = kperm_inv(kp);
    float x = src[(ks << 5) + c];
    u16 hb = f2bf(x);
    outv[j] = half ? f2bf(x - bf2f(hb)) : hb;
  }
  *(u16x8*)(pk + (size_t)u * 8) = *(u16x8*)outv;
}

// ---------------------------------------------------------------------------
// Kernel A: scores[h][n][t] = o_k[n] . tanh(Wm[h] @ mk[n,t])
// Block: 512 thr (8 waves, 2 m-strips x 4 e-strips), tile 128t x 256e, K=256 in
// 8 steps of 32. Split-bf16 compensation: acc += ah*bh + ah*bl + al*bh.
// ---------------------------------------------------------------------------
__global__ __launch_bounds__(512, 4) void k_scores(
    const float* __restrict__ mk, const float* __restrict__ ok,
    const u16* __restrict__ pk, float* __restrict__ sc) {
  __shared__ u16 Ahi[128][40];   // 32 + 8 pad -> 80B rows, conflict-free b128
  __shared__ u16 Alo[128][40];
  __shared__ u16 Bt[2][8192];    // hi 16KB | lo 16KB, linear gl_lds image
  __shared__ float red[128][4];

  const int bid = blockIdx.x;
  const int g = ((bid & 7) << 9) + (bid >> 3);   // XCD-contiguous logical id
  const int h = g & 7;
  const int n = (g >> 3) & 31;
  const int tb = g >> 8;
  const int tid = threadIdx.x;
  const int wave = tid >> 6;
  const int lane = tid & 63;
  const int wr = wave >> 2;
  const int wc = wave & 3;
  const int l15 = lane & 15;
  const int lg = lane >> 4;

  f32x4 acc[4][4];
#pragma unroll
  for (int i = 0; i < 4; ++i) {
#pragma unroll
    for (int j = 0; j < 4; ++j) acc[i][j] = (f32x4){0.f, 0.f, 0.f, 0.f};
  }

  const float* Ag = mk + ((size_t)n * TT + (size_t)tb * 128) * DD;
  const u16* Bg = pk + (size_t)h * 8 * 16384;

  const int ar = tid >> 2;            // 0..127 tile row
  const int acg = (tid & 3) << 3;     // source k group within kstep
  const int ap0 = kperm(acg);         // contiguous-4 destination positions
  const int ap1 = kperm(acg + 4);

  for (int ks = 0; ks < 8; ++ks) {
    __syncthreads();
    // B: async global -> LDS, 32KB = 32 chunks of 1KB
    const u16* bsrc = Bg + (size_t)ks * 16384;
#pragma unroll
    for (int i = 0; i < 4; ++i) {
      const int chunk = (i << 3) + wave;
      gl_lds16(bsrc + (chunk << 9) + (lane << 3), &Bt[0][0] + (chunk << 9));
    }
    // A: fp32 load + split-bf16 convert + ds_write (k-permuted)
    {
      const float* a = Ag + (size_t)ar * DD + (ks << 5) + acg;
      f4 v0 = *(const f4*)a;
      f4 v1 = *(const f4*)(a + 4);
      float xs[8] = {v0.x, v0.y, v0.z, v0.w, v1.x, v1.y, v1.z, v1.w};
      u16 hi[8], lo[8];
#pragma unroll
      for (int j = 0; j < 8; ++j) {
        u16 hb = f2bf(xs[j]);
        hi[j] = hb;
        lo[j] = f2bf(xs[j] - bf2f(hb));
      }
      *(u16x4*)&Ahi[ar][ap0] = (u16x4){hi[0], hi[1], hi[2], hi[3]};
      *(u16x4*)&Ahi[ar][ap1] = (u16x4){hi[4], hi[5], hi[6], hi[7]};
      *(u16x4*)&Alo[ar][ap0] = (u16x4){lo[0], lo[1], lo[2], lo[3]};
      *(u16x4*)&Alo[ar][ap1] = (u16x4){lo[4], lo[5], lo[6], lo[7]};
    }
    __syncthreads();

    bf16x8 ah[4], al[4];
#pragma unroll
    for (int mi = 0; mi < 4; ++mi) {
      const int row = (wr << 6) + (mi << 4) + l15;
      ah[mi] = *(const bf16x8*)&Ahi[row][lg << 3];
      al[mi] = *(const bf16x8*)&Alo[row][lg << 3];
    }
#pragma unroll
    for (int ni = 0; ni < 4; ++ni) {
      const int e = (wc << 6) + (ni << 4) + l15;
      const int off = (e << 5) + ((lg << 3) ^ (((e >> 1) & 3) << 3));
      bf16x8 bh = *(const bf16x8*)&Bt[0][off];
      bf16x8 bl = *(const bf16x8*)&Bt[1][off];
#pragma unroll
      for (int mi = 0; mi < 4; ++mi) {
        acc[mi][ni] = __builtin_amdgcn_mfma_f32_16x16x32_bf16(ah[mi], bh, acc[mi][ni], 0, 0, 0);
        acc[mi][ni] = __builtin_amdgcn_mfma_f32_16x16x32_bf16(ah[mi], bl, acc[mi][ni], 0, 0, 0);
        acc[mi][ni] = __builtin_amdgcn_mfma_f32_16x16x32_bf16(al[mi], bh, acc[mi][ni], 0, 0, 0);
      }
    }
  }

  // Epilogue: s[t] = sum_e tanh(P[t,e]) * ok[e]
  float okv[4];
#pragma unroll
  for (int ni = 0; ni < 4; ++ni) okv[ni] = ok[(n << 8) + (wc << 6) + (ni << 4) + l15];
#pragma unroll
  for (int mi = 0; mi < 4; ++mi) {
#pragma unroll
    for (int j = 0; j < 4; ++j) {
      float s = 0.f;
#pragma unroll
      for (int ni = 0; ni < 4; ++ni) s += ftanh(acc[mi][ni][j]) * okv[ni];
      s += __shfl_xor(s, 1);
      s += __shfl_xor(s, 2);
      s += __shfl_xor(s, 4);
      s += __shfl_xor(s, 8);
      if (l15 == 0) red[(wr << 6) + (mi << 4) + (lg << 2) + j][wc] = s;
    }
  }
  __syncthreads();
  if (tid < 128) {
    float v = red[tid][0] + red[tid][1] + red[tid][2] + red[tid][3];
    sc[(((size_t)h * 32 + n) << 11) + tb * 128 + tid] = v;
  }
}

// ---------------------------------------------------------------------------
// Kernel B: softmax over T per (h,n) row, in place.
// ---------------------------------------------------------------------------
__global__ void k_softmax(float* __restrict__ sc) {
  __shared__ float sm[8];
  const int row = blockIdx.x, tid = threadIdx.x;
  float* base = sc + ((size_t)row << 11);
  f4 a = *(const f4*)(base + tid * 8);
  f4 b = *(const f4*)(base + tid * 8 + 4);
  float m = fmaxf(fmaxf(fmaxf(a.x, a.y), fmaxf(a.z, a.w)),
                  fmaxf(fmaxf(b.x, b.y), fmaxf(b.z, b.w)));
#pragma unroll
  for (int o = 1; o < 64; o <<= 1) m = fmaxf(m, __shfl_xor(m, o));
  if ((tid & 63) == 0) sm[tid >> 6] = m;
  __syncthreads();
  m = fmaxf(fmaxf(sm[0], sm[1]), fmaxf(sm[2], sm[3]));
  a.x = __expf(a.x - m); a.y = __expf(a.y - m); a.z = __expf(a.z - m); a.w = __expf(a.w - m);
  b.x = __expf(b.x - m); b.y = __expf(b.y - m); b.z = __expf(b.z - m); b.w = __expf(b.w - m);
  float s = a.x + a.y + a.z + a.w + b.x + b.y + b.z + b.w;
#pragma unroll
  for (int o = 1; o < 64; o <<= 1) s += __shfl_xor(s, o);
  if ((tid & 63) == 0) sm[4 + (tid >> 6)] = s;
  __syncthreads();
  s = sm[4] + sm[5] + sm[6] + sm[7];
  float inv = 1.f / s;
  a.x *= inv; a.y *= inv; a.z *= inv; a.w *= inv;
  b.x *= inv; b.y *= inv; b.z *= inv; b.w *= inv;
  *(f4*)(base + tid * 8) = a;
  *(f4*)(base + tid * 8 + 4) = b;
}

// ---------------------------------------------------------------------------
// Kernel C: partial rep over t-slices of 128: rp[n][sl][h*256+d]
// ---------------------------------------------------------------------------
__global__ void k_rep(const float* __restrict__ mv, const float* __restrict__ p,
                      float* __restrict__ rp) {
  __shared__ float pl[8][128];
  const int b = blockIdx.x;
  const int n = b >> 4, sl = b & 15;
  const int tid = threadIdx.x;
  for (int i = tid; i < 1024; i += 256) {
    int h = i >> 7, t = i & 127;
    pl[h][t] = p[(((size_t)h * 32 + n) << 11) + sl * 128 + t];
  }
  __syncthreads();
  float r[8] = {0.f, 0.f, 0.f, 0.f, 0.f, 0.f, 0.f, 0.f};
  const float* src = mv + (((size_t)n << 11) + sl * 128) * DD + tid;
#pragma unroll 4
  for (int tt = 0; tt < 128; ++tt) {
    float v = src[(size_t)tt * DD];
#pragma unroll
    for (int h = 0; h < 8; ++h) r[h] = fmaf(pl[h][tt], v, r[h]);
  }
  float* dst = rp + (((size_t)n * 16 + sl) << 11) + tid;
#pragma unroll
  for (int h = 0; h < 8; ++h) dst[h * 256] = r[h];
}

// ---------------------------------------------------------------------------
// Kernel D: out[n][i] = b[i] + sum_j concat[n][j] * Wo_w[i][j]
// ---------------------------------------------------------------------------
__global__ void k_out(const float* __restrict__ rp, const float* __restrict__ w,
                      const float* __restrict__ bias, float* __restrict__ out) {
  __shared__ float c[2048];
  const int n = blockIdx.x, tid = threadIdx.x;
  for (int j = tid; j < 2048; j += 256) {
    float s = 0.f;
#pragma unroll
    for (int sl = 0; sl < 16; ++sl) s += rp[(((size_t)n * 16 + sl) << 11) + j];
    c[j] = s;
  }
  __syncthreads();
  float acc = bias[tid];
  const f4* wrow = (const f4*)(w + (size_t)tid * 2048);
  const f4* cc = (const f4*)c;
  for (int j = 0; j < 512; ++j) {
    f4 wv = wrow[j];
    f4 cv = cc[j];
    acc += wv.x * cv.x + wv.y * cv.y + wv.z * cv.z + wv.w * cv.w;
  }
  out[n * 256 + tid] = acc;
}

extern "C" void kernel_launch(void* const* d_in, const int* in_sizes, int n_in,
                              void* d_out, int out_size, void* d_ws, size_t ws_size,
                              hipStream_t stream) {
  const float* ok  = (const float*)d_in[0];
  const float* mk  = (const float*)d_in[1];
  const float* mv  = (const float*)d_in[2];
  const float* wm  = (const float*)d_in[3];
  const float* wow = (const float*)d_in[4];
  const float* wob = (const float*)d_in[5];
  float* out = (float*)d_out;
  char* ws = (char*)d_ws;
  // ws layout: [0,2MB) scores/probs  [2MB,4MB) Wm pack  [4MB,8MB) rep partials
  float* sc = (float*)ws;
  u16* pkb  = (u16*)(ws + (2u << 20));
  float* rp = (float*)(ws + (4u << 20));

  hipLaunchKernelGGL(k_pack,    dim3(512),  dim3(256), 0, stream, wm, pkb);
  hipLaunchKernelGGL(k_scores,  dim3(4096), dim3(512), 0, stream, mk, ok, pkb, sc);
  hipLaunchKernelGGL(k_softmax, dim3(256),  dim3(256), 0, stream, sc);
  hipLaunchKernelGGL(k_rep,     dim3(512),  dim3(256), 0, stream, mv, sc, rp);
  hipLaunchKernelGGL(k_out,     dim3(32),   dim3(256), 0, stream, rp, wow, wob, out);
}